// Round 19
// baseline (127.604 us; speedup 1.0000x reference)
//
#include <hip/hip_runtime.h>
#include <hip/hip_cooperative_groups.h>
#include <math.h>

namespace cg = cooperative_groups;

#define B_     16
#define NX_    8192
#define C_     128
#define K1_    17          // kx + 1 retained frequencies
#define QW_    20          // padded trig-row width in float2 (160 B)
#define NC_    16          // chunks; chunk owns 256 lo-rows + hi partners (+NX/2)
#define NSP_   256         // pairs per chunk
#define NCI_   64          // inverse chunks (64 rows each)
#define NH_    4096        // NX/2

typedef float v2f __attribute__((ext_vector_type(2)));
typedef float v4f __attribute__((ext_vector_type(4)));

// Workspace layout (floats):
//   Gpart : [B][K1][2(cos,sin)][NC][C]  k-major   (4.45 MB)
//   Acoef : [B][K1][C] float2 (ar, ai)            (0.28 MB)
//   TrigG : [4096 rows][2*QW_] flat               (0.64 MB)
#define GPART_F  ((size_t)B_ * K1_ * 2 * NC_ * C_)
#define ACOEF_F  ((size_t)B_ * K1_ * C_ * 2)
#define TRIG_OFF (GPART_F + ACOEF_F)

// ===========================================================================
// Phase bodies as __device__ helpers (shared by fused and fallback paths).
// ===========================================================================

__device__ __forceinline__ void fwd_body(const float* __restrict__ x,
                                         float* __restrict__ ws,
                                         v4f* smem, int b, int c, int t) {
    float* gpart = ws;
    const int jq  = t & 31;             // channel quad: 4*jq .. 4*jq+3
    const int sub = (t >> 5) & 1;       // k-parity half (0: even, 1: odd)
    const int w   = t >> 6;             // wave id
    const int i0  = c * NSP_;

    const size_t xb = (size_t)b * NX_ * C_;
    const int ibase = w * 64;           // this wave's local pair range
    const float sg = sub ? -1.f : 1.f;  // (-1)^k for this lane's k-parity
    const float* xlo_p = x + xb + (size_t)(i0 + ibase) * C_ + 4 * jq;
    const float* xhi_p = xlo_p + (size_t)NH_ * C_;

    // issue group-0 x loads FIRST — independent of trig; overlaps the build
    v4f bl[2][4], bh[2][4];
#pragma unroll
    for (int j = 0; j < 4; ++j) {
        bl[0][j] = *(const v4f*)(xlo_p + (size_t)j * C_);
        bh[0][j] = *(const v4f*)(xhi_p + (size_t)j * C_);
    }

    // build trig table (LDS) and dump to flat global table (b==0 only)
    {
        float2* tg  = (float2*)smem;
        float2* tgg = (float2*)(ws + TRIG_OFF) + (size_t)i0 * QW_;
        for (int idx = t; idx < NSP_ * QW_; idx += 256) {
            int i = idx / QW_;
            int q = idx - i * QW_;
            float2 v = make_float2(0.f, 0.f);
            int k = (q < 9) ? (2 * q) : ((q >= 10 && q < 18) ? (2 * (q - 10) + 1) : -1);
            if (k >= 0) {
                int m = (k * (i0 + i)) & (NX_ - 1);
                float rev = (float)m * (1.0f / (float)NX_);   // exact
                v = make_float2(__builtin_amdgcn_cosf(rev),
                                __builtin_amdgcn_sinf(rev));
            }
            tg[idx] = v;
            if (b == 0) tgg[idx] = v;
        }
    }
    __syncthreads();

    v4f gr[9], gs[9];
#pragma unroll
    for (int kk = 0; kk < 9; ++kk) { gr[kk] = (v4f)(0.f); gs[kk] = (v4f)(0.f); }

    const float* tp = (const float*)smem + ((size_t)ibase * QW_ + sub * 10) * 2;

#pragma unroll
    for (int g = 0; g < 16; ++g) {
        const int cur = g & 1, nxt = cur ^ 1;
        if (g < 15) {
#pragma unroll
            for (int j = 0; j < 4; ++j) {   // prefetch next group (8 b128)
                bl[nxt][j] = *(const v4f*)(xlo_p + (size_t)((g + 1) * 4 + j) * C_);
                bh[nxt][j] = *(const v4f*)(xhi_p + (size_t)((g + 1) * 4 + j) * C_);
            }
        }
#pragma unroll
        for (int j = 0; j < 4; ++j) {
            const int s = g * 4 + j;
            v4f xs = __builtin_elementwise_fma(bh[cur][j], (v4f)(sg), bl[cur][j]);
            const float* tr = tp + (size_t)s * (2 * QW_);
            float4 t0 = *(const float4*)(tr + 0);
            float4 t1 = *(const float4*)(tr + 4);
            float4 t2 = *(const float4*)(tr + 8);
            float4 t3 = *(const float4*)(tr + 12);
            float2 t4 = *(const float2*)(tr + 16);
            gr[0] = __builtin_elementwise_fma(xs, (v4f)(t0.x), gr[0]);
            gs[0] = __builtin_elementwise_fma(xs, (v4f)(t0.y), gs[0]);
            gr[1] = __builtin_elementwise_fma(xs, (v4f)(t0.z), gr[1]);
            gs[1] = __builtin_elementwise_fma(xs, (v4f)(t0.w), gs[1]);
            gr[2] = __builtin_elementwise_fma(xs, (v4f)(t1.x), gr[2]);
            gs[2] = __builtin_elementwise_fma(xs, (v4f)(t1.y), gs[2]);
            gr[3] = __builtin_elementwise_fma(xs, (v4f)(t1.z), gr[3]);
            gs[3] = __builtin_elementwise_fma(xs, (v4f)(t1.w), gs[3]);
            gr[4] = __builtin_elementwise_fma(xs, (v4f)(t2.x), gr[4]);
            gs[4] = __builtin_elementwise_fma(xs, (v4f)(t2.y), gs[4]);
            gr[5] = __builtin_elementwise_fma(xs, (v4f)(t2.z), gr[5]);
            gs[5] = __builtin_elementwise_fma(xs, (v4f)(t2.w), gs[5]);
            gr[6] = __builtin_elementwise_fma(xs, (v4f)(t3.x), gr[6]);
            gs[6] = __builtin_elementwise_fma(xs, (v4f)(t3.y), gs[6]);
            gr[7] = __builtin_elementwise_fma(xs, (v4f)(t3.z), gr[7]);
            gs[7] = __builtin_elementwise_fma(xs, (v4f)(t3.w), gs[7]);
            gr[8] = __builtin_elementwise_fma(xs, (v4f)(t4.x), gr[8]);
            gs[8] = __builtin_elementwise_fma(xs, (v4f)(t4.y), gs[8]);
        }
    }

    // two-round cross-wave reduction (reuses trig LDS; stride 19 v4f)
    const int lid = t & 63;
    __syncthreads();
    if (w >= 2) {
        v4f* p = smem + ((size_t)(w - 2) * 64 + lid) * 19;
#pragma unroll
        for (int kk = 0; kk < 9; ++kk) { p[2 * kk] = gr[kk]; p[2 * kk + 1] = gs[kk]; }
    }
    __syncthreads();
    if (w < 2) {
        const v4f* p = smem + ((size_t)w * 64 + lid) * 19;
#pragma unroll
        for (int kk = 0; kk < 9; ++kk) { gr[kk] += p[2 * kk]; gs[kk] += p[2 * kk + 1]; }
    }
    __syncthreads();
    if (w == 1) {
        v4f* p = smem + (size_t)lid * 19;
#pragma unroll
        for (int kk = 0; kk < 9; ++kk) { p[2 * kk] = gr[kk]; p[2 * kk + 1] = gs[kk]; }
    }
    __syncthreads();
    if (w == 0) {
        const v4f* p = smem + (size_t)lid * 19;
#pragma unroll
        for (int kk = 0; kk < 9; ++kk) {
            gr[kk] += p[2 * kk];
            gs[kk] += p[2 * kk + 1];
            if (sub == 0 || kk < 8) {
                int k = sub ? 2 * kk + 1 : 2 * kk;
                float* gpR = gpart + ((((size_t)b * K1_ + k) * 2 + 0) * NC_ + c) * C_ + 4 * jq;
                float* gpS = gpart + ((((size_t)b * K1_ + k) * 2 + 1) * NC_ + c) * C_ + 4 * jq;
                *(v4f*)gpR = gr[kk];
                *(v4f*)gpS = gs[kk];
            }
        }
    }
}

// 256-thread mix job: reduce 16 slots + complex weight matmul for one (b,k).
__device__ __forceinline__ void mix_body(const float* __restrict__ wr_g,
                                         const float* __restrict__ wi_g,
                                         float* __restrict__ ws,
                                         float* smemf, int bb, int k, int t) {
    const float* gpart = ws;
    float2* acoef = (float2*)(ws + GPART_F);
    const int i = t & 127;
    const int h = t >> 7;
    float* grs = smemf;
    float* gss = grs + C_;
    float* trr = gss + C_;
    float* tii = trr + C_;

    const float* baseR = gpart + (((size_t)bb * K1_ + k) * 2 + 0) * ((size_t)NC_ * C_);
    const float* baseS = gpart + (((size_t)bb * K1_ + k) * 2 + 1) * ((size_t)NC_ * C_);
    float gr = 0.f, gs = 0.f;
#pragma unroll
    for (int s = 0; s < 8; ++s) {
        gr += baseR[(size_t)(h * 8 + s) * C_ + i];
        gs += baseS[(size_t)(h * 8 + s) * C_ + i];
    }
    if (h) { trr[i] = gr; tii[i] = gs; }
    __syncthreads();
    if (!h) { grs[i] = gr + trr[i]; gss[i] = gs + tii[i]; }
    __syncthreads();

    // H = W * (gr - i*gs):  hr = wr*gr + wi*gs ; hi = wi*gr - wr*gs
    float hr = 0.f, hi = 0.f;
    const float* wrp = wr_g + ((size_t)k * C_ + i) * C_;
    const float* wip = wi_g + ((size_t)k * C_ + i) * C_;
#pragma unroll 8
    for (int jj = h * 64; jj < h * 64 + 64; ++jj) {
        float wr = wrp[jj], wi = wip[jj];
        float a = grs[jj], cc = gss[jj];
        hr = fmaf(wr, a, hr); hr = fmaf( wi, cc, hr);
        hi = fmaf(wi, a, hi); hi = fmaf(-wr, cc, hi);
    }
    __syncthreads();
    if (h) { trr[i] = hr; tii[i] = hi; }
    __syncthreads();
    if (!h) {
        hr += trr[i]; hi += tii[i];
        // out[n] = sum_k c_k*(hr*cos - hi*sin) -> ar = c*hr, ai = -c*hi
        float cf = (k == 0 ? 1.0f : 2.0f) / (float)NX_;
        acoef[((size_t)bb * K1_ + k) * C_ + i] = make_float2(cf * hr, -cf * hi);
    }
    __syncthreads();    // protect LDS before next job reuses it
}

__device__ __forceinline__ void inv_body(float* __restrict__ out,
                                         const float* __restrict__ ws,
                                         int b, int c, int t) {
    const float4* acoef4 = (const float4*)(ws + GPART_F);
    const float* trigg = ws + TRIG_OFF;
    const int jp = t & 63;
    const int h = __builtin_amdgcn_readfirstlane(t >> 6);
    const int i0 = c * 64;

    v2f arE[9], aiE[9], arO[8], aiO[8];
#pragma unroll
    for (int q = 0; q < 9; ++q) {
        float4 a = acoef4[((size_t)b * K1_ + 2 * q) * (C_ / 2) + jp];
        arE[q] = (v2f){a.x, a.z}; aiE[q] = (v2f){a.y, a.w};
    }
#pragma unroll
    for (int q = 0; q < 8; ++q) {
        float4 a = acoef4[((size_t)b * K1_ + 2 * q + 1) * (C_ / 2) + jp];
        arO[q] = (v2f){a.x, a.z}; aiO[q] = (v2f){a.y, a.w};
    }

    const float* trow = trigg + ((size_t)(i0 + h * 16)) * (2 * QW_);
    const size_t ob = (size_t)b * NX_ * C_;
    float* olo = out + ob + (size_t)(i0 + h * 16) * C_ + 2 * jp;
    float* ohi = olo + (size_t)NH_ * C_;

#pragma unroll 4
    for (int s = 0; s < 16; ++s) {
        const float* tr = trow + (size_t)s * (2 * QW_);   // wave-uniform row
        float4 e0 = *(const float4*)(tr + 0);
        float4 e1 = *(const float4*)(tr + 4);
        float4 e2 = *(const float4*)(tr + 8);
        float4 e3 = *(const float4*)(tr + 12);
        float2 e4 = *(const float2*)(tr + 16);
        float4 o0 = *(const float4*)(tr + 20);
        float4 o1 = *(const float4*)(tr + 24);
        float4 o2 = *(const float4*)(tr + 28);
        float4 o3 = *(const float4*)(tr + 32);
        v2f Se = (v2f)(0.f), So = (v2f)(0.f);
        Se = __builtin_elementwise_fma(arE[0], (v2f)(e0.x), Se);
        Se = __builtin_elementwise_fma(aiE[0], (v2f)(e0.y), Se);
        Se = __builtin_elementwise_fma(arE[1], (v2f)(e0.z), Se);
        Se = __builtin_elementwise_fma(aiE[1], (v2f)(e0.w), Se);
        Se = __builtin_elementwise_fma(arE[2], (v2f)(e1.x), Se);
        Se = __builtin_elementwise_fma(aiE[2], (v2f)(e1.y), Se);
        Se = __builtin_elementwise_fma(arE[3], (v2f)(e1.z), Se);
        Se = __builtin_elementwise_fma(aiE[3], (v2f)(e1.w), Se);
        Se = __builtin_elementwise_fma(arE[4], (v2f)(e2.x), Se);
        Se = __builtin_elementwise_fma(aiE[4], (v2f)(e2.y), Se);
        Se = __builtin_elementwise_fma(arE[5], (v2f)(e2.z), Se);
        Se = __builtin_elementwise_fma(aiE[5], (v2f)(e2.w), Se);
        Se = __builtin_elementwise_fma(arE[6], (v2f)(e3.x), Se);
        Se = __builtin_elementwise_fma(aiE[6], (v2f)(e3.y), Se);
        Se = __builtin_elementwise_fma(arE[7], (v2f)(e3.z), Se);
        Se = __builtin_elementwise_fma(aiE[7], (v2f)(e3.w), Se);
        Se = __builtin_elementwise_fma(arE[8], (v2f)(e4.x), Se);
        Se = __builtin_elementwise_fma(aiE[8], (v2f)(e4.y), Se);
        So = __builtin_elementwise_fma(arO[0], (v2f)(o0.x), So);
        So = __builtin_elementwise_fma(aiO[0], (v2f)(o0.y), So);
        So = __builtin_elementwise_fma(arO[1], (v2f)(o0.z), So);
        So = __builtin_elementwise_fma(aiO[1], (v2f)(o0.w), So);
        So = __builtin_elementwise_fma(arO[2], (v2f)(o1.x), So);
        So = __builtin_elementwise_fma(aiO[2], (v2f)(o1.y), So);
        So = __builtin_elementwise_fma(arO[3], (v2f)(o1.z), So);
        So = __builtin_elementwise_fma(aiO[3], (v2f)(o1.w), So);
        So = __builtin_elementwise_fma(arO[4], (v2f)(o2.x), So);
        So = __builtin_elementwise_fma(aiO[4], (v2f)(o2.y), So);
        So = __builtin_elementwise_fma(arO[5], (v2f)(o2.z), So);
        So = __builtin_elementwise_fma(aiO[5], (v2f)(o2.w), So);
        So = __builtin_elementwise_fma(arO[6], (v2f)(o3.x), So);
        So = __builtin_elementwise_fma(aiO[6], (v2f)(o3.y), So);
        So = __builtin_elementwise_fma(arO[7], (v2f)(o3.z), So);
        So = __builtin_elementwise_fma(aiO[7], (v2f)(o3.w), So);
        *(v2f*)(olo + (size_t)s * C_) = Se + So;        // ascending stream
        *(v2f*)(ohi + (size_t)s * C_) = Se - So;        // ascending stream
    }
}

// ===========================================================================
// Fused cooperative kernel: 256 blocks (1/CU), grid-stride phases,
// cg grid sync at the two boundaries. Eliminates 2 dispatch ramps/drains.
// ===========================================================================
__global__ __launch_bounds__(256) void k_all(
        const float* __restrict__ x,
        const float* __restrict__ wr_g,
        const float* __restrict__ wi_g,
        float* __restrict__ out,
        float* __restrict__ ws) {
    __shared__ v4f smem[2560];          // 40960 B
    const int bid = blockIdx.x;
    const int t = threadIdx.x;

    // phase 1: forward DFT — 256 tiles, 1:1 with blocks
    fwd_body(x, ws, smem, bid >> 4, bid & 15, t);

    cg::this_grid().sync();

    // phase 2: mix — 272 jobs over 256 blocks
    for (int job = bid; job < B_ * K1_; job += 256)
        mix_body(wr_g, wi_g, ws, (float*)smem, job / K1_, job % K1_, t);

    cg::this_grid().sync();

    // phase 3: inverse — 1024 tiles over 256 blocks
    for (int tile = bid; tile < B_ * NCI_; tile += 256)
        inv_body(out, ws, tile >> 6, tile & 63, t);
}

// ===========================================================================
// Fallback: proven round-18 three-kernel pipeline (identical bodies).
// ===========================================================================
__global__ __launch_bounds__(256) void k_fwd(const float* __restrict__ x,
                                             float* __restrict__ ws) {
    __shared__ v4f smem[2560];
    fwd_body(x, ws, smem, blockIdx.y, blockIdx.x, threadIdx.x);
}

__global__ __launch_bounds__(1024) void k_mix(const float* __restrict__ wr_g,
                                              const float* __restrict__ wi_g,
                                              float* __restrict__ ws) {
    const int k = blockIdx.x, b = blockIdx.y, t = threadIdx.x;
    const float* gpart = ws;
    float2* acoef = (float2*)(ws + GPART_F);
    __shared__ float part[8][C_];
    __shared__ float gsum[2][C_];
    __shared__ float hp[16][C_];
    {
        const int ch = t & 127, ri = (t >> 7) & 1, sh = t >> 8;   // sh 0..3
        const float* base = gpart + (((size_t)b * K1_ + k) * 2 + ri) * ((size_t)NC_ * C_) + ch;
        float g = 0.f;
#pragma unroll
        for (int s = 0; s < 4; ++s) g += base[(size_t)(sh * 4 + s) * C_];
        part[sh * 2 + ri][ch] = g;
    }
    __syncthreads();
    if (t < 256) {
        const int ch = t & 127, ri = t >> 7;
        gsum[ri][ch] = part[ri][ch] + part[2 + ri][ch] + part[4 + ri][ch] + part[6 + ri][ch];
    }
    __syncthreads();
    {
        const int i = t & 127, q = t >> 7;
        float hr = 0.f, hi = 0.f;
        const float* wrp = wr_g + ((size_t)k * C_ + i) * C_;
        const float* wip = wi_g + ((size_t)k * C_ + i) * C_;
#pragma unroll
        for (int jjj = 0; jjj < 16; ++jjj) {
            int jj = q * 16 + jjj;
            float wr = wrp[jj], wi = wip[jj];
            float a = gsum[0][jj], cc = gsum[1][jj];
            hr = fmaf(wr, a, hr); hr = fmaf( wi, cc, hr);
            hi = fmaf(wi, a, hi); hi = fmaf(-wr, cc, hi);
        }
        hp[q * 2 + 0][i] = hr;
        hp[q * 2 + 1][i] = hi;
    }
    __syncthreads();
    if (t < 128) {
        const int i = t;
        float hr = 0.f, hi = 0.f;
#pragma unroll
        for (int q = 0; q < 8; ++q) { hr += hp[q * 2][i]; hi += hp[q * 2 + 1][i]; }
        float cf = (k == 0 ? 1.0f : 2.0f) / (float)NX_;
        acoef[((size_t)b * K1_ + k) * C_ + i] = make_float2(cf * hr, -cf * hi);
    }
}

__global__ __launch_bounds__(256) void k_inv(float* __restrict__ out,
                                             const float* __restrict__ ws) {
    inv_body(out, ws, blockIdx.y, blockIdx.x, threadIdx.x);
}

extern "C" void kernel_launch(void* const* d_in, const int* in_sizes, int n_in,
                              void* d_out, int out_size, void* d_ws, size_t ws_size,
                              hipStream_t stream) {
    const float* x  = (const float*)d_in[0];   // (B, NX, C) fp32
    const float* wr = (const float*)d_in[1];   // (K1, C, C) fp32
    const float* wi = (const float*)d_in[2];   // (K1, C, C) fp32
    float* out = (float*)d_out;                // (B, NX, C) fp32
    float* ws  = (float*)d_ws;                 // ~5.4 MB used

    void* args[] = { (void*)&x, (void*)&wr, (void*)&wi, (void*)&out, (void*)&ws };
    hipError_t err = hipLaunchCooperativeKernel((void*)k_all, dim3(256), dim3(256),
                                                args, 0, stream);
    if (err != hipSuccess) {
        // fallback: proven 3-kernel pipeline (identical math)
        k_fwd<<<dim3(NC_, B_), 256, 0, stream>>>(x, ws);
        k_mix<<<dim3(K1_, B_), 1024, 0, stream>>>(wr, wi, ws);
        k_inv<<<dim3(NCI_, B_), 256, 0, stream>>>(out, ws);
    }
}

// Round 20
// 45.397 us; speedup vs baseline: 2.8109x; 2.8109x over previous
//
#include <hip/hip_runtime.h>
#include <math.h>

#define B_     16
#define NX_    8192
#define C_     128
#define K1_    17          // kx + 1 retained frequencies
#define QW_    20          // padded trig-row width in float2 (160 B)
#define NC_    16          // chunks; chunk owns 256 lo-rows + hi partners (+NX/2)
#define NSP_   256         // pairs per chunk
#define NCI_   64          // inverse chunks (64 rows each)
#define NH_    4096        // NX/2

typedef float v2f __attribute__((ext_vector_type(2)));
typedef float v4f __attribute__((ext_vector_type(4)));

// Workspace layout (floats):
//   Gpart : [B][K1][2(cos,sin)][NC][C]  k-major   (4.45 MB)
//   Acoef : [B][K1][C] float2 (ar, ai)            (0.28 MB)
//   TrigG : [4096 rows][2*QW_] flat               (0.64 MB)
#define GPART_F  ((size_t)B_ * K1_ * 2 * NC_ * C_)
#define ACOEF_F  ((size_t)B_ * K1_ * C_ * 2)
#define TRIG_OFF (GPART_F + ACOEF_F)

// trig row (float2 index q): q<9 -> even k=2q ; q==9 pad ; 10<=q<18 -> odd
// k=2(q-10)+1 ; q>=18 pad. Row = 40 floats = 160 B.

// ---------------------------------------------------------------------------
// Forward truncated DFT, folded over n <-> n+NH:
//   G_k = sum_{n<NH} (x[n] + (-1)^k x[n+NH]) e^{-i th_kn}
// Lane = (jq: channel quad, sub: k-parity half). Software-pipelined x loads:
// 16 groups of 4 steps, double-buffered registers. Group-0 loads are issued
// BEFORE the trig build so HBM ramp/latency overlaps the serial prologue.
// ---------------------------------------------------------------------------
__global__ __launch_bounds__(256) void k_fwd(const float* __restrict__ x,
                                             float* __restrict__ ws) {
    __shared__ v4f smem[2560];          // 40960 B; trig 40960 B, reduction 38912 B

    float* gpart = ws;
    const int b = blockIdx.y;
    const int c = blockIdx.x;
    const int t = threadIdx.x;
    const int jq  = t & 31;             // channel quad: 4*jq .. 4*jq+3
    const int sub = (t >> 5) & 1;       // k-parity half (0: even, 1: odd)
    const int w   = t >> 6;             // wave id
    const int i0  = c * NSP_;

    const size_t xb = (size_t)b * NX_ * C_;
    const int ibase = w * 64;           // this wave's local pair range
    const float sg = sub ? -1.f : 1.f;  // (-1)^k for this lane's k-parity
    const float* xlo_p = x + xb + (size_t)(i0 + ibase) * C_ + 4 * jq;
    const float* xhi_p = xlo_p + (size_t)NH_ * C_;

    // issue group-0 x loads FIRST — independent of trig; overlaps the build
    v4f bl[2][4], bh[2][4];
#pragma unroll
    for (int j = 0; j < 4; ++j) {
        bl[0][j] = *(const v4f*)(xlo_p + (size_t)j * C_);
        bh[0][j] = *(const v4f*)(xhi_p + (size_t)j * C_);
    }

    // build trig table (LDS) and dump to flat global table (b==0 only)
    {
        float2* tg  = (float2*)smem;
        float2* tgg = (float2*)(ws + TRIG_OFF) + (size_t)i0 * QW_;
        for (int idx = t; idx < NSP_ * QW_; idx += 256) {
            int i = idx / QW_;
            int q = idx - i * QW_;
            float2 v = make_float2(0.f, 0.f);
            int k = (q < 9) ? (2 * q) : ((q >= 10 && q < 18) ? (2 * (q - 10) + 1) : -1);
            if (k >= 0) {
                int m = (k * (i0 + i)) & (NX_ - 1);
                float rev = (float)m * (1.0f / (float)NX_);   // exact
                v = make_float2(__builtin_amdgcn_cosf(rev),
                                __builtin_amdgcn_sinf(rev));
            }
            tg[idx] = v;
            if (b == 0) tgg[idx] = v;
        }
    }
    __syncthreads();

    v4f gr[9], gs[9];
#pragma unroll
    for (int kk = 0; kk < 9; ++kk) { gr[kk] = (v4f)(0.f); gs[kk] = (v4f)(0.f); }

    const float* tp = (const float*)smem + ((size_t)ibase * QW_ + sub * 10) * 2;

#pragma unroll
    for (int g = 0; g < 16; ++g) {
        const int cur = g & 1, nxt = cur ^ 1;
        if (g < 15) {
#pragma unroll
            for (int j = 0; j < 4; ++j) {   // prefetch next group (8 b128)
                bl[nxt][j] = *(const v4f*)(xlo_p + (size_t)((g + 1) * 4 + j) * C_);
                bh[nxt][j] = *(const v4f*)(xhi_p + (size_t)((g + 1) * 4 + j) * C_);
            }
        }
#pragma unroll
        for (int j = 0; j < 4; ++j) {
            const int s = g * 4 + j;
            v4f xs = __builtin_elementwise_fma(bh[cur][j], (v4f)(sg), bl[cur][j]);
            const float* tr = tp + (size_t)s * (2 * QW_);
            float4 t0 = *(const float4*)(tr + 0);
            float4 t1 = *(const float4*)(tr + 4);
            float4 t2 = *(const float4*)(tr + 8);
            float4 t3 = *(const float4*)(tr + 12);
            float2 t4 = *(const float2*)(tr + 16);
            gr[0] = __builtin_elementwise_fma(xs, (v4f)(t0.x), gr[0]);
            gs[0] = __builtin_elementwise_fma(xs, (v4f)(t0.y), gs[0]);
            gr[1] = __builtin_elementwise_fma(xs, (v4f)(t0.z), gr[1]);
            gs[1] = __builtin_elementwise_fma(xs, (v4f)(t0.w), gs[1]);
            gr[2] = __builtin_elementwise_fma(xs, (v4f)(t1.x), gr[2]);
            gs[2] = __builtin_elementwise_fma(xs, (v4f)(t1.y), gs[2]);
            gr[3] = __builtin_elementwise_fma(xs, (v4f)(t1.z), gr[3]);
            gs[3] = __builtin_elementwise_fma(xs, (v4f)(t1.w), gs[3]);
            gr[4] = __builtin_elementwise_fma(xs, (v4f)(t2.x), gr[4]);
            gs[4] = __builtin_elementwise_fma(xs, (v4f)(t2.y), gs[4]);
            gr[5] = __builtin_elementwise_fma(xs, (v4f)(t2.z), gr[5]);
            gs[5] = __builtin_elementwise_fma(xs, (v4f)(t2.w), gs[5]);
            gr[6] = __builtin_elementwise_fma(xs, (v4f)(t3.x), gr[6]);
            gs[6] = __builtin_elementwise_fma(xs, (v4f)(t3.y), gs[6]);
            gr[7] = __builtin_elementwise_fma(xs, (v4f)(t3.z), gr[7]);
            gs[7] = __builtin_elementwise_fma(xs, (v4f)(t3.w), gs[7]);
            gr[8] = __builtin_elementwise_fma(xs, (v4f)(t4.x), gr[8]);
            gs[8] = __builtin_elementwise_fma(xs, (v4f)(t4.y), gs[8]);
        }
    }

    // two-round cross-wave reduction (reuses trig LDS; stride 19 v4f)
    const int lid = t & 63;
    __syncthreads();
    if (w >= 2) {
        v4f* p = smem + ((size_t)(w - 2) * 64 + lid) * 19;
#pragma unroll
        for (int kk = 0; kk < 9; ++kk) { p[2 * kk] = gr[kk]; p[2 * kk + 1] = gs[kk]; }
    }
    __syncthreads();
    if (w < 2) {
        const v4f* p = smem + ((size_t)w * 64 + lid) * 19;
#pragma unroll
        for (int kk = 0; kk < 9; ++kk) { gr[kk] += p[2 * kk]; gs[kk] += p[2 * kk + 1]; }
    }
    __syncthreads();
    if (w == 1) {
        v4f* p = smem + (size_t)lid * 19;
#pragma unroll
        for (int kk = 0; kk < 9; ++kk) { p[2 * kk] = gr[kk]; p[2 * kk + 1] = gs[kk]; }
    }
    __syncthreads();
    if (w == 0) {
        const v4f* p = smem + (size_t)lid * 19;
#pragma unroll
        for (int kk = 0; kk < 9; ++kk) {
            gr[kk] += p[2 * kk];
            gs[kk] += p[2 * kk + 1];
            if (sub == 0 || kk < 8) {
                int k = sub ? 2 * kk + 1 : 2 * kk;
                float* gpR = gpart + ((((size_t)b * K1_ + k) * 2 + 0) * NC_ + c) * C_ + 4 * jq;
                float* gpS = gpart + ((((size_t)b * K1_ + k) * 2 + 1) * NC_ + c) * C_ + 4 * jq;
                *(v4f*)gpR = gr[kk];
                *(v4f*)gpS = gs[kk];
            }
        }
    }
}

// ---------------------------------------------------------------------------
// Reduce NC slots + complex weight matmul, 1024 threads for latency hiding.
// ---------------------------------------------------------------------------
__global__ __launch_bounds__(1024) void k_mix(const float* __restrict__ wr_g,
                                              const float* __restrict__ wi_g,
                                              float* __restrict__ ws) {
    const int k = blockIdx.x, b = blockIdx.y, t = threadIdx.x;
    const float* gpart = ws;
    float2* acoef = (float2*)(ws + GPART_F);
    __shared__ float part[8][C_];
    __shared__ float gsum[2][C_];
    __shared__ float hp[16][C_];
    {
        const int ch = t & 127, ri = (t >> 7) & 1, sh = t >> 8;   // sh 0..3
        const float* base = gpart + (((size_t)b * K1_ + k) * 2 + ri) * ((size_t)NC_ * C_) + ch;
        float g = 0.f;
#pragma unroll
        for (int s = 0; s < 4; ++s) g += base[(size_t)(sh * 4 + s) * C_];
        part[sh * 2 + ri][ch] = g;
    }
    __syncthreads();
    if (t < 256) {
        const int ch = t & 127, ri = t >> 7;
        gsum[ri][ch] = part[ri][ch] + part[2 + ri][ch] + part[4 + ri][ch] + part[6 + ri][ch];
    }
    __syncthreads();
    {
        const int i = t & 127, q = t >> 7;
        float hr = 0.f, hi = 0.f;
        const float* wrp = wr_g + ((size_t)k * C_ + i) * C_;
        const float* wip = wi_g + ((size_t)k * C_ + i) * C_;
#pragma unroll
        for (int jjj = 0; jjj < 16; ++jjj) {
            int jj = q * 16 + jjj;
            float wr = wrp[jj], wi = wip[jj];
            float a = gsum[0][jj], cc = gsum[1][jj];
            hr = fmaf(wr, a, hr); hr = fmaf( wi, cc, hr);
            hi = fmaf(wi, a, hi); hi = fmaf(-wr, cc, hi);
        }
        hp[q * 2 + 0][i] = hr;
        hp[q * 2 + 1][i] = hi;
    }
    __syncthreads();
    if (t < 128) {
        const int i = t;
        float hr = 0.f, hi = 0.f;
#pragma unroll
        for (int q = 0; q < 8; ++q) { hr += hp[q * 2][i]; hi += hp[q * 2 + 1][i]; }
        // out[n] = sum_k c_k*(hr*cos - hi*sin) -> ar = c*hr, ai = -c*hi
        float cf = (k == 0 ? 1.0f : 2.0f) / (float)NX_;
        acoef[((size_t)b * K1_ + k) * C_ + i] = make_float2(cf * hr, -cf * hi);
    }
}

// ---------------------------------------------------------------------------
// Inverse, folded over n <-> n+NH: Se = even-k terms, So = odd-k terms;
// out[n] = Se+So, out[n+NH] = Se-So. Trig from flat global table via
// wave-uniform rows (compiler-scheduled). Zero LDS, zero barriers.
// ---------------------------------------------------------------------------
__global__ __launch_bounds__(256) void k_inv(float* __restrict__ out,
                                             const float* __restrict__ ws) {
    const float4* acoef4 = (const float4*)(ws + GPART_F);
    const float* trigg = ws + TRIG_OFF;
    const int b = blockIdx.y, c = blockIdx.x, t = threadIdx.x;
    const int jp = t & 63;
    const int h = __builtin_amdgcn_readfirstlane(t >> 6);
    const int i0 = c * 64;

    v2f arE[9], aiE[9], arO[8], aiO[8];
#pragma unroll
    for (int q = 0; q < 9; ++q) {
        float4 a = acoef4[((size_t)b * K1_ + 2 * q) * (C_ / 2) + jp];
        arE[q] = (v2f){a.x, a.z}; aiE[q] = (v2f){a.y, a.w};
    }
#pragma unroll
    for (int q = 0; q < 8; ++q) {
        float4 a = acoef4[((size_t)b * K1_ + 2 * q + 1) * (C_ / 2) + jp];
        arO[q] = (v2f){a.x, a.z}; aiO[q] = (v2f){a.y, a.w};
    }

    const float* trow = trigg + ((size_t)(i0 + h * 16)) * (2 * QW_);
    const size_t ob = (size_t)b * NX_ * C_;
    float* olo = out + ob + (size_t)(i0 + h * 16) * C_ + 2 * jp;
    float* ohi = olo + (size_t)NH_ * C_;

#pragma unroll 4
    for (int s = 0; s < 16; ++s) {
        const float* tr = trow + (size_t)s * (2 * QW_);   // wave-uniform row
        float4 e0 = *(const float4*)(tr + 0);
        float4 e1 = *(const float4*)(tr + 4);
        float4 e2 = *(const float4*)(tr + 8);
        float4 e3 = *(const float4*)(tr + 12);
        float2 e4 = *(const float2*)(tr + 16);
        float4 o0 = *(const float4*)(tr + 20);
        float4 o1 = *(const float4*)(tr + 24);
        float4 o2 = *(const float4*)(tr + 28);
        float4 o3 = *(const float4*)(tr + 32);
        v2f Se = (v2f)(0.f), So = (v2f)(0.f);
        Se = __builtin_elementwise_fma(arE[0], (v2f)(e0.x), Se);
        Se = __builtin_elementwise_fma(aiE[0], (v2f)(e0.y), Se);
        Se = __builtin_elementwise_fma(arE[1], (v2f)(e0.z), Se);
        Se = __builtin_elementwise_fma(aiE[1], (v2f)(e0.w), Se);
        Se = __builtin_elementwise_fma(arE[2], (v2f)(e1.x), Se);
        Se = __builtin_elementwise_fma(aiE[2], (v2f)(e1.y), Se);
        Se = __builtin_elementwise_fma(arE[3], (v2f)(e1.z), Se);
        Se = __builtin_elementwise_fma(aiE[3], (v2f)(e1.w), Se);
        Se = __builtin_elementwise_fma(arE[4], (v2f)(e2.x), Se);
        Se = __builtin_elementwise_fma(aiE[4], (v2f)(e2.y), Se);
        Se = __builtin_elementwise_fma(arE[5], (v2f)(e2.z), Se);
        Se = __builtin_elementwise_fma(aiE[5], (v2f)(e2.w), Se);
        Se = __builtin_elementwise_fma(arE[6], (v2f)(e3.x), Se);
        Se = __builtin_elementwise_fma(aiE[6], (v2f)(e3.y), Se);
        Se = __builtin_elementwise_fma(arE[7], (v2f)(e3.z), Se);
        Se = __builtin_elementwise_fma(aiE[7], (v2f)(e3.w), Se);
        Se = __builtin_elementwise_fma(arE[8], (v2f)(e4.x), Se);
        Se = __builtin_elementwise_fma(aiE[8], (v2f)(e4.y), Se);
        So = __builtin_elementwise_fma(arO[0], (v2f)(o0.x), So);
        So = __builtin_elementwise_fma(aiO[0], (v2f)(o0.y), So);
        So = __builtin_elementwise_fma(arO[1], (v2f)(o0.z), So);
        So = __builtin_elementwise_fma(aiO[1], (v2f)(o0.w), So);
        So = __builtin_elementwise_fma(arO[2], (v2f)(o1.x), So);
        So = __builtin_elementwise_fma(aiO[2], (v2f)(o1.y), So);
        So = __builtin_elementwise_fma(arO[3], (v2f)(o1.z), So);
        So = __builtin_elementwise_fma(aiO[3], (v2f)(o1.w), So);
        So = __builtin_elementwise_fma(arO[4], (v2f)(o2.x), So);
        So = __builtin_elementwise_fma(aiO[4], (v2f)(o2.y), So);
        So = __builtin_elementwise_fma(arO[5], (v2f)(o2.z), So);
        So = __builtin_elementwise_fma(aiO[5], (v2f)(o2.w), So);
        So = __builtin_elementwise_fma(arO[6], (v2f)(o3.x), So);
        So = __builtin_elementwise_fma(aiO[6], (v2f)(o3.y), So);
        So = __builtin_elementwise_fma(arO[7], (v2f)(o3.z), So);
        So = __builtin_elementwise_fma(aiO[7], (v2f)(o3.w), So);
        *(v2f*)(olo + (size_t)s * C_) = Se + So;        // ascending stream
        *(v2f*)(ohi + (size_t)s * C_) = Se - So;        // ascending stream
    }
}

extern "C" void kernel_launch(void* const* d_in, const int* in_sizes, int n_in,
                              void* d_out, int out_size, void* d_ws, size_t ws_size,
                              hipStream_t stream) {
    const float* x  = (const float*)d_in[0];   // (B, NX, C) fp32
    const float* wr = (const float*)d_in[1];   // (K1, C, C) fp32
    const float* wi = (const float*)d_in[2];   // (K1, C, C) fp32
    float* out = (float*)d_out;                // (B, NX, C) fp32
    float* ws  = (float*)d_ws;                 // ~5.4 MB used

    k_fwd<<<dim3(NC_, B_), 256, 0, stream>>>(x, ws);
    k_mix<<<dim3(K1_, B_), 1024, 0, stream>>>(wr, wi, ws);
    k_inv<<<dim3(NCI_, B_), 256, 0, stream>>>(out, ws);
}